// Round 3
// baseline (111.864 us; speedup 1.0000x reference)
//
#include <hip/hip_runtime.h>
#include <math.h>

#define NCONCEPT 1024

typedef float fx4 __attribute__((ext_vector_type(4)));
typedef int   ix4 __attribute__((ext_vector_type(4)));
typedef float fx2 __attribute__((ext_vector_type(2)));

// out[i] = 0.5 + 0.5 * ( cos(th2)*cos(th1) - sin(th2)*sin(th1)*cos(om1 + ph2) )
//        = 0.5 + 0.5 * ( A*c1 - s1*(Bc*co - Bs*so) )
// with A = cos(th2), Bc = sin(th2)*cos(ph2), Bs = sin(th2)*sin(ph2),
//      (s1,c1) = sincos(th1 = instance[i][1]), (so,co) = sincos(om1 = instance[i][2]),
//      ph2 = w[idx[i]][0], th2 = w[idx[i]][1].
// instance[i][0] and w[..][2] cancel out of <Z> exactly.

__global__ __launch_bounds__(256) void vqc_kernel(
    const float* __restrict__ inst,   // [N,3] f32
    const int*   __restrict__ idx,    // [N]   i32
    const float* __restrict__ w,      // [NCONCEPT,3] f32
    float*       __restrict__ out,    // [N]   f32
    int n)
{
    // Split tables: random b32/b64 gathers spread over all 32 banks
    // (a float4 table has only 8 bank-groups -> ~8-way conflicts).
    __shared__ float tabA[NCONCEPT];   // cos(th2)
    __shared__ fx2   tabB[NCONCEPT];   // (sin th2 * cos ph2, sin th2 * sin ph2)

    for (int c = threadIdx.x; c < NCONCEPT; c += blockDim.x) {
        float ph2 = w[c * 3 + 0];
        float th2 = w[c * 3 + 1];
        float sth2, cth2, sph2, cph2;
        __sincosf(th2, &sth2, &cth2);
        __sincosf(ph2, &sph2, &cph2);
        tabA[c] = cth2;
        fx2 b; b.x = sth2 * cph2; b.y = sth2 * sph2;
        tabB[c] = b;
    }
    __syncthreads();

    const int tid    = blockIdx.x * blockDim.x + threadIdx.x;
    const int stride = gridDim.x * blockDim.x;
    const int nocts  = n >> 3;          // 8 elements per iteration

    const fx4* __restrict__ inst4 = (const fx4*)inst;
    const ix4* __restrict__ idx4  = (const ix4*)idx;
    fx4*       __restrict__ out4  = (fx4*)out;

    for (int q = tid; q < nocts; q += stride) {
        // 8 elements = 24 floats = 6x float4; issue ALL global loads upfront
        fx4 a0 = __builtin_nontemporal_load(&inst4[q * 6 + 0]);
        fx4 a1 = __builtin_nontemporal_load(&inst4[q * 6 + 1]);
        fx4 a2 = __builtin_nontemporal_load(&inst4[q * 6 + 2]);
        fx4 a3 = __builtin_nontemporal_load(&inst4[q * 6 + 3]);
        fx4 a4 = __builtin_nontemporal_load(&inst4[q * 6 + 4]);
        fx4 a5 = __builtin_nontemporal_load(&inst4[q * 6 + 5]);
        ix4 i0 = __builtin_nontemporal_load(&idx4[q * 2 + 0]);
        ix4 i1 = __builtin_nontemporal_load(&idx4[q * 2 + 1]);

        // element e: floats (3e, 3e+1, 3e+2) = (phi, theta, omega)
        float th[8] = { a0.y, a1.x, a1.w, a2.z, a3.y, a4.x, a4.w, a5.z };
        float om[8] = { a0.z, a1.y, a2.x, a2.w, a3.z, a4.y, a5.x, a5.w };
        int   id[8] = { i0.x, i0.y, i0.z, i0.w, i1.x, i1.y, i1.z, i1.w };

        float res[8];
        #pragma unroll
        for (int e = 0; e < 8; ++e) {
            float A  = tabA[id[e]];
            fx2   Bv = tabB[id[e]];
            float s1, c1, so, co;
            __sincosf(th[e], &s1, &c1);
            __sincosf(om[e], &so, &co);
            float cop = Bv.x * co - Bv.y * so;   // sin(th2)*cos(om1+ph2)
            float z   = A * c1 - s1 * cop;
            res[e] = fmaf(z, 0.5f, 0.5f);
        }
        fx4 r0, r1;
        r0.x = res[0]; r0.y = res[1]; r0.z = res[2]; r0.w = res[3];
        r1.x = res[4]; r1.y = res[5]; r1.z = res[6]; r1.w = res[7];
        __builtin_nontemporal_store(r0, &out4[q * 2 + 0]);
        __builtin_nontemporal_store(r1, &out4[q * 2 + 1]);
    }

    // scalar tail (n not divisible by 8) — no-op for this problem size
    for (int i = (nocts << 3) + tid; i < n; i += stride) {
        float th1 = inst[i * 3 + 1];
        float om1 = inst[i * 3 + 2];
        float A   = tabA[idx[i]];
        fx2   Bv  = tabB[idx[i]];
        float s1, c1, so, co;
        __sincosf(th1, &s1, &c1);
        __sincosf(om1, &so, &co);
        float z = A * c1 - s1 * (Bv.x * co - Bv.y * so);
        out[i] = fmaf(z, 0.5f, 0.5f);
    }
}

extern "C" void kernel_launch(void* const* d_in, const int* in_sizes, int n_in,
                              void* d_out, int out_size, void* d_ws, size_t ws_size,
                              hipStream_t stream) {
    const float* inst = (const float*)d_in[0];   // [B,D,3] f32
    const int*   idx  = (const int*)d_in[1];     // [B,D]   i32
    const float* w    = (const float*)d_in[2];   // [NC,3]  f32
    float*       out  = (float*)d_out;           // [B,D]   f32

    const int n = in_sizes[1];                   // B*D elements
    const int blocks = 2048;                     // all-resident grid, 4 octs/thread
    vqc_kernel<<<blocks, 256, 0, stream>>>(inst, idx, w, out, n);
}

// Round 4
// 66.996 us; speedup vs baseline: 1.6697x; 1.6697x over previous
//
#include <hip/hip_runtime.h>
#include <math.h>

#define NCONCEPT 1024
#define TILE 1024          // elements per block-iteration
#define TPB  256

typedef float fx4 __attribute__((ext_vector_type(4)));
typedef int   ix4 __attribute__((ext_vector_type(4)));
typedef float fx2 __attribute__((ext_vector_type(2)));

// out[i] = 0.5 + 0.5 * ( cos(th2)*cos(th1) - sin(th2)*sin(th1)*cos(om1 + ph2) )
//        = 0.5 + 0.5 * ( A*c1 - s1*(Bc*co - Bs*so) )
// A = cos(th2), Bc = sin(th2)*cos(ph2), Bs = sin(th2)*sin(ph2);
// th1 = instance[i][1], om1 = instance[i][2]; ph2 = w[idx[i]][0], th2 = w[idx[i]][1].
// instance[i][0] and w[..][2] cancel out of <Z> exactly.
//
// Instance tile is staged through LDS so ALL global traffic is coalesced
// fx4/ix4 (round-1's 48B/lane strided reads were 1/3 line-efficient).
// LDS pad: +4 words per 32 (keeps 16B alignment for fx4 writes; breaks the
// 12-word read stride's 8-way bank aliasing down to <=2-way, which is free).

__device__ __forceinline__ int padw(int wd) { return wd + 4 * (wd >> 5); }

__global__ __launch_bounds__(TPB) void vqc_kernel(
    const float* __restrict__ inst,   // [N,3] f32
    const int*   __restrict__ idx,    // [N]   i32
    const float* __restrict__ w,      // [NCONCEPT,3] f32
    float*       __restrict__ out,    // [N]   f32
    int n)
{
    __shared__ float tabA[NCONCEPT];              // cos(th2)
    __shared__ fx2   tabB[NCONCEPT];              // (sth2*cph2, sth2*sph2)
    __shared__ float sd[TILE * 3 + 4 * ((TILE * 3) / 32)];  // 3456 floats

    for (int c = threadIdx.x; c < NCONCEPT; c += TPB) {
        float ph2 = w[c * 3 + 0];
        float th2 = w[c * 3 + 1];
        float sth2, cth2, sph2, cph2;
        __sincosf(th2, &sth2, &cth2);
        __sincosf(ph2, &sph2, &cph2);
        tabA[c] = cth2;
        fx2 b; b.x = sth2 * cph2; b.y = sth2 * sph2;
        tabB[c] = b;
    }
    // (first __syncthreads below also covers table visibility)

    const int tid    = threadIdx.x;
    const int ntiles = (n + TILE - 1) / TILE;

    for (int tile = blockIdx.x; tile < ntiles; tile += gridDim.x) {
        const int base = tile * TILE;

        if (base + TILE <= n) {
            // ---- coalesced stage: 3*TILE floats = 768 fx4 ----
            const fx4* __restrict__ src = (const fx4*)(inst + (size_t)base * 3);
            #pragma unroll
            for (int k = 0; k < 3; ++k) {
                fx4 v = src[k * TPB + tid];
                int wd = (k * TPB + tid) * 4;
                *(fx4*)&sd[padw(wd)] = v;
            }
            ix4 iv = ((const ix4*)(idx + base))[tid];   // elements 4t..4t+3
            __syncthreads();

            float res[4];
            #pragma unroll
            for (int j = 0; j < 4; ++j) {
                int e  = tid * 4 + j;
                int w1 = e * 3 + 1;
                int w2 = e * 3 + 2;
                float th = sd[padw(w1)];
                float om = sd[padw(w2)];
                int   id = (j == 0) ? iv.x : (j == 1) ? iv.y : (j == 2) ? iv.z : iv.w;
                float A  = tabA[id];
                fx2   Bv = tabB[id];
                float s1, c1, so, co;
                __sincosf(th, &s1, &c1);
                __sincosf(om, &so, &co);
                float z = A * c1 - s1 * (Bv.x * co - Bv.y * so);
                res[j] = fmaf(z, 0.5f, 0.5f);
            }
            fx4 r; r.x = res[0]; r.y = res[1]; r.z = res[2]; r.w = res[3];
            ((fx4*)(out + base))[tid] = r;
            __syncthreads();   // before next tile overwrites sd
        } else {
            // scalar tail tile (block-uniform branch; no sd use -> no sync)
            for (int i = base + tid; i < n; i += TPB) {
                float th1 = inst[i * 3 + 1];
                float om1 = inst[i * 3 + 2];
                float A   = tabA[idx[i]];
                fx2   Bv  = tabB[idx[i]];
                float s1, c1, so, co;
                __sincosf(th1, &s1, &c1);
                __sincosf(om1, &so, &co);
                float z = A * c1 - s1 * (Bv.x * co - Bv.y * so);
                out[i] = fmaf(z, 0.5f, 0.5f);
            }
        }
    }
}

extern "C" void kernel_launch(void* const* d_in, const int* in_sizes, int n_in,
                              void* d_out, int out_size, void* d_ws, size_t ws_size,
                              hipStream_t stream) {
    const float* inst = (const float*)d_in[0];   // [B,D,3] f32
    const int*   idx  = (const int*)d_in[1];     // [B,D]   i32
    const float* w    = (const float*)d_in[2];   // [NC,3]  f32
    float*       out  = (float*)d_out;           // [B,D]   f32

    const int n = in_sizes[1];                   // B*D elements
    const int ntiles = (n + TILE - 1) / TILE;
    // 26 KB LDS/block -> 6 blocks/CU -> 1536 resident; launch exactly that
    // so grid-stride work assignment matches residency (no makespan cliff).
    int blocks = 1536;
    if (blocks > ntiles) blocks = ntiles;
    vqc_kernel<<<blocks, TPB, 0, stream>>>(inst, idx, w, out, n);
}

// Round 5
// 66.367 us; speedup vs baseline: 1.6855x; 1.0095x over previous
//
#include <hip/hip_runtime.h>
#include <math.h>

#define NCONCEPT 1024
#define TILE 1024            // elements per tile (3072 floats = 12 KB)
#define TPB  256
#define NJ   (TILE / TPB)    // 4 elements per thread per tile

typedef float fx4 __attribute__((ext_vector_type(4)));

// out[i] = 0.5 + 0.5 * ( cos(th2)*cos(th1) - sin(th2)*sin(th1)*cos(om1 + ph2) )
//        = 0.5 + 0.5 * ( A*c1 - s1*(Bc*co - Bs*so) )
// A = cos(th2), Bc = sin(th2)*cos(ph2), Bs = sin(th2)*sin(ph2);
// th1 = instance[i][1], om1 = instance[i][2]; ph2/th2 = w[idx[i]][0/1].
// instance[i][0] and w[..][2] cancel out of <Z> exactly.
//
// Design (R5): coalesced fx4 staging -> linear LDS (ds_write_b128,
// conflict-free) -> compute threads read elements at stride-TPB so the
// 3-word element stride maps gcd(3,32)=1 -> 2-way bank aliasing (free).
// Next tile's instance+idx prefetched into registers during compute (T14).

__global__ __launch_bounds__(TPB) void vqc_kernel(
    const float* __restrict__ inst,   // [N,3] f32
    const int*   __restrict__ idx,    // [N]   i32
    const float* __restrict__ w,      // [NCONCEPT,3] f32
    float*       __restrict__ out,    // [N]   f32
    int n)
{
    __shared__ fx4   tab[NCONCEPT];   // (A, Bc, Bs, 0) — 16 KB
    __shared__ float sd[TILE * 3];    // linear instance tile — 12 KB

    for (int c = threadIdx.x; c < NCONCEPT; c += TPB) {
        float ph2 = w[c * 3 + 0];
        float th2 = w[c * 3 + 1];
        float sth2, cth2, sph2, cph2;
        __sincosf(th2, &sth2, &cth2);
        __sincosf(ph2, &sph2, &cph2);
        fx4 t; t.x = cth2; t.y = sth2 * cph2; t.z = sth2 * sph2; t.w = 0.0f;
        tab[c] = t;
    }

    const int tid    = threadIdx.x;
    const int ntiles = n / TILE;
    const int stride = gridDim.x;
    int tile = blockIdx.x;

    // ---- prefetch first tile into registers ----
    fx4 A0, A1, A2;
    int iv[NJ];
    if (tile < ntiles) {
        const fx4* __restrict__ src = (const fx4*)(inst + (size_t)tile * TILE * 3);
        A0 = src[0 * TPB + tid];
        A1 = src[1 * TPB + tid];
        A2 = src[2 * TPB + tid];
        const int* __restrict__ ip = idx + (size_t)tile * TILE;
        #pragma unroll
        for (int j = 0; j < NJ; ++j) iv[j] = ip[tid + j * TPB];
    }
    __syncthreads();   // table ready

    while (tile < ntiles) {
        const int next = tile + stride;

        // ---- stage current tile: conflict-free b128 writes ----
        {
            fx4* dst = (fx4*)sd;
            dst[0 * TPB + tid] = A0;
            dst[1 * TPB + tid] = A1;
            dst[2 * TPB + tid] = A2;
        }
        int cv[NJ];
        #pragma unroll
        for (int j = 0; j < NJ; ++j) cv[j] = iv[j];

        // ---- issue next tile's loads (latency hides under compute) ----
        if (next < ntiles) {
            const fx4* __restrict__ src = (const fx4*)(inst + (size_t)next * TILE * 3);
            A0 = src[0 * TPB + tid];
            A1 = src[1 * TPB + tid];
            A2 = src[2 * TPB + tid];
            const int* __restrict__ ip = idx + (size_t)next * TILE;
            #pragma unroll
            for (int j = 0; j < NJ; ++j) iv[j] = ip[tid + j * TPB];
        }
        __syncthreads();   // sd visible

        // ---- compute: stride-TPB elements, 2-way (free) LDS reads ----
        const int base = tile * TILE;
        #pragma unroll
        for (int j = 0; j < NJ; ++j) {
            const int e  = tid + j * TPB;
            float th = sd[3 * e + 1];
            float om = sd[3 * e + 2];
            fx4 t4 = tab[cv[j]];
            float s1, c1, so, co;
            __sincosf(th, &s1, &c1);
            __sincosf(om, &so, &co);
            float z = t4.x * c1 - s1 * (t4.y * co - t4.z * so);
            out[base + e] = fmaf(z, 0.5f, 0.5f);
        }
        __syncthreads();   // all reads of sd done before next overwrite
        tile = next;
    }

    // ---- scalar tail (n % TILE) — empty for N = 2^24, kept for safety ----
    const int tail0 = ntiles * TILE;
    for (int i = tail0 + blockIdx.x * TPB + tid; i < n; i += gridDim.x * TPB) {
        float th1 = inst[i * 3 + 1];
        float om1 = inst[i * 3 + 2];
        fx4 t4 = tab[idx[i]];
        float s1, c1, so, co;
        __sincosf(th1, &s1, &c1);
        __sincosf(om1, &so, &co);
        float z = t4.x * c1 - s1 * (t4.y * co - t4.z * so);
        out[i] = fmaf(z, 0.5f, 0.5f);
    }
}

extern "C" void kernel_launch(void* const* d_in, const int* in_sizes, int n_in,
                              void* d_out, int out_size, void* d_ws, size_t ws_size,
                              hipStream_t stream) {
    const float* inst = (const float*)d_in[0];   // [B,D,3] f32
    const int*   idx  = (const int*)d_in[1];     // [B,D]   i32
    const float* w    = (const float*)d_in[2];   // [NC,3]  f32
    float*       out  = (float*)d_out;           // [B,D]   f32

    const int n = in_sizes[1];                   // B*D elements
    const int ntiles = n / TILE;
    // 28 KB LDS/block -> 5 blocks/CU -> 1280 resident blocks
    int blocks = 1280;
    if (blocks > ntiles) blocks = ntiles > 0 ? ntiles : 1;
    vqc_kernel<<<blocks, TPB, 0, stream>>>(inst, idx, w, out, n);
}